// Round 1
// baseline (2448.670 us; speedup 1.0000x reference)
//
#include <hip/hip_runtime.h>
#include <math.h>

#define Bn 64
#define Nn 16384
#define Mn 64
#define Cn 256
#define MP2 66
#define GAMMA 0.95f
#define EPSF 1e-16f

// ---------------- Kernel 1: projection o = emb @ W^T + b -> k, beta, g, ||k|| ----------------
__global__ __launch_bounds__(128) void k1_proj(
    const float* __restrict__ emb, const float* __restrict__ W,
    const float* __restrict__ bias,
    float* __restrict__ ws_k, float* __restrict__ ws_beta,
    float* __restrict__ ws_g, float* __restrict__ ws_normk,
    float* __restrict__ ws_denom) {
  int b = blockIdx.x;
  int tid = threadIdx.x;
  __shared__ float emb_s[Cn];
  __shared__ float k_s[Mn];
  if (tid == 0) ws_denom[b] = 0.0f;  // re-zero every launch (graph replay safe: k2 runs after)
  for (int c = tid; c < Cn; c += blockDim.x) emb_s[c] = emb[(size_t)b * Cn + c];
  __syncthreads();
  if (tid < MP2) {
    float sum = bias[tid];
    const float* wrow = W + (size_t)tid * Cn;
    #pragma unroll 4
    for (int c = 0; c < Cn; ++c) sum += emb_s[c] * wrow[c];
    if (tid < Mn) {
      ws_k[(size_t)b * Mn + tid] = sum;
      k_s[tid] = sum;
    } else if (tid == Mn) {
      // stable softplus: max(x,0) + log1p(exp(-|x|))
      ws_beta[b] = fmaxf(sum, 0.0f) + log1pf(expf(-fabsf(sum)));
    } else {
      ws_g[b] = 1.0f / (1.0f + expf(-sum));
    }
  }
  __syncthreads();
  if (tid < 64) {
    float v = k_s[tid] * k_s[tid];
    #pragma unroll
    for (int o = 32; o > 0; o >>= 1) v += __shfl_xor(v, o, 64);
    if (tid == 0) ws_normk[b] = sqrtf(v);
  }
}

// ---------------- Kernel 2: fused cosine-sim + exp + denom-accum + memory update ----------------
// One 16-lane group per memory row (M=64 floats = 16 x float4). 4 rows per wave,
// 16 rows per 256-thread block. Reads memory once; writes new_memory + unnormalized p.
// Softmax shift uses the constant bound beta (sim <= 1), so no global max pass is needed:
//   p = exp(beta*sim - beta), denom accumulated with one atomicAdd per wave.
__global__ __launch_bounds__(256) void k2_main(
    const float* __restrict__ memory, const float* __restrict__ w_prev,
    const float* __restrict__ ws_k, const float* __restrict__ ws_g,
    const float* __restrict__ ws_normk, const float* __restrict__ ws_beta,
    float* __restrict__ p_out, float* __restrict__ new_mem,
    float* __restrict__ ws_denom) {
  const int ROWS_PER_BLOCK = 16;
  const int blocks_per_b = Nn / ROWS_PER_BLOCK;  // 1024
  int b = blockIdx.x / blocks_per_b;
  int n_base = (blockIdx.x % blocks_per_b) * ROWS_PER_BLOCK;
  int tid = threadIdx.x;
  int wave = tid >> 6;
  int lane = tid & 63;
  int row_in_wave = lane >> 4;   // 0..3
  int col4 = lane & 15;          // which float4 of the row
  int n = n_base + wave * 4 + row_in_wave;

  size_t off = ((size_t)b * Nn + n) * Mn + (size_t)col4 * 4;
  const float4 m4 = *(const float4*)(memory + off);
  const float4 k4 = *(const float4*)(ws_k + (size_t)b * Mn + (size_t)col4 * 4);

  float g = ws_g[b];
  float wr_p  = w_prev[((size_t)b * 3 + 1) * Nn + n];
  float wlu_p = w_prev[((size_t)b * 3 + 2) * Nn + n];
  float ww = g * wr_p + (1.0f - g) * wlu_p;

  float dkm = m4.x * k4.x + m4.y * k4.y + m4.z * k4.z + m4.w * k4.w;
  float dmm = m4.x * m4.x + m4.y * m4.y + m4.z * m4.z + m4.w * m4.w;
  #pragma unroll
  for (int o = 8; o >= 1; o >>= 1) {   // reduce within 16-lane groups
    dkm += __shfl_xor(dkm, o, 64);
    dmm += __shfl_xor(dmm, o, 64);
  }

  float4 o4;
  o4.x = m4.x + ww * k4.x;
  o4.y = m4.y + ww * k4.y;
  o4.z = m4.z + ww * k4.z;
  o4.w = m4.w + ww * k4.w;
  *(float4*)(new_mem + off) = o4;

  // all 16 lanes of a group hold the reduced dkm/dmm
  float sim = dkm / (ws_normk[b] * sqrtf(dmm) + EPSF);
  float beta = ws_beta[b];
  float e = expf(beta * (sim - 1.0f));   // unnormalized prob, shift = const upper bound
  if (col4 == 0) p_out[(size_t)b * Nn + n] = e;

  // per-wave denom partial: lanes 0,16,32,48 hold the 4 distinct row values
  float ec = (col4 == 0) ? e : 0.0f;
  ec += __shfl_xor(ec, 16, 64);
  ec += __shfl_xor(ec, 32, 64);
  if (lane == 0) atomicAdd(&ws_denom[b], ec);
}

// ---------------- Kernel 3: normalize, w_u, top-4 min -> w planes ----------------
// No softmax reductions left: denom already accumulated by k2. Vectorized float4 I/O.
__global__ __launch_bounds__(1024) void k3_finish(
    const float* __restrict__ w_prev, const float* __restrict__ p_in,
    const float* __restrict__ ws_g, const float* __restrict__ ws_denom,
    float* __restrict__ w_out) {
  int b = blockIdx.x;
  int tid = threadIdx.x;
  int lane = tid & 63, wid = tid >> 6;  // 16 waves
  float g = ws_g[b];
  float inv = 1.0f / ws_denom[b];

  const float* pb     = p_in   + (size_t)b * Nn;
  const float* wup_p  = w_prev + ((size_t)b * 3 + 0) * Nn;
  const float* wrp_p  = w_prev + ((size_t)b * 3 + 1) * Nn;
  const float* wlup_p = w_prev + ((size_t)b * 3 + 2) * Nn;
  float* wu_out  = w_out + ((size_t)b * 3 + 0) * Nn;
  float* wr_out  = w_out + ((size_t)b * 3 + 1) * Nn;
  float* wlu_out = w_out + ((size_t)b * 3 + 2) * Nn;

  // 16 elements per thread as 4 x float4 (coalesced 16B/lane)
  float wu_loc[16];
  #pragma unroll
  for (int i = 0; i < 4; ++i) {
    int n0 = i * 4096 + tid * 4;
    float4 p4   = *(const float4*)(pb + n0);
    float4 u4   = *(const float4*)(wup_p + n0);
    float4 r4   = *(const float4*)(wrp_p + n0);
    float4 l4   = *(const float4*)(wlup_p + n0);
    float4 wr4, wu4;
    wr4.x = p4.x * inv; wr4.y = p4.y * inv; wr4.z = p4.z * inv; wr4.w = p4.w * inv;
    float wwx = g * r4.x + (1.0f - g) * l4.x;
    float wwy = g * r4.y + (1.0f - g) * l4.y;
    float wwz = g * r4.z + (1.0f - g) * l4.z;
    float www = g * r4.w + (1.0f - g) * l4.w;
    wu4.x = GAMMA * u4.x + wr4.x + wwx;
    wu4.y = GAMMA * u4.y + wr4.y + wwy;
    wu4.z = GAMMA * u4.z + wr4.z + wwz;
    wu4.w = GAMMA * u4.w + wr4.w + www;
    *(float4*)(wu_out + n0) = wu4;
    *(float4*)(wr_out + n0) = wr4;
    wu_loc[i * 4 + 0] = wu4.x;
    wu_loc[i * 4 + 1] = wu4.y;
    wu_loc[i * 4 + 2] = wu4.z;
    wu_loc[i * 4 + 3] = wu4.w;
  }

  // top-4 smallest w_u, ties -> lower index (matches jax.lax.top_k on -w_u).
  // unique key = (orderable_float_bits << 32) | index; min key == min value, lowest idx.
  unsigned long long key_loc[16];
  #pragma unroll
  for (int i = 0; i < 4; ++i) {
    #pragma unroll
    for (int j = 0; j < 4; ++j) {
      unsigned int n = (unsigned int)(i * 4096 + tid * 4 + j);
      unsigned int bits = __float_as_uint(wu_loc[i * 4 + j]);
      bits ^= (bits >> 31) ? 0xFFFFFFFFu : 0x80000000u;  // total order incl. negatives
      key_loc[i * 4 + j] = ((unsigned long long)bits << 32) | n;
    }
  }

  __shared__ unsigned long long red_k[16];
  __shared__ unsigned long long best_s;
  unsigned long long chosen[4] = {~0ull, ~0ull, ~0ull, ~0ull};

  for (int r = 0; r < 4; ++r) {
    unsigned long long bk = ~0ull;
    #pragma unroll
    for (int i = 0; i < 16; ++i) {
      unsigned long long k = key_loc[i];
      bool excl = (k == chosen[0]) | (k == chosen[1]) | (k == chosen[2]) | (k == chosen[3]);
      if (!excl && k < bk) bk = k;
    }
    #pragma unroll
    for (int o = 32; o > 0; o >>= 1) {
      unsigned long long ok = __shfl_xor(bk, o, 64);
      if (ok < bk) bk = ok;
    }
    if (lane == 0) red_k[wid] = bk;
    __syncthreads();
    if (tid == 0) {
      unsigned long long m = red_k[0];
      for (int i = 1; i < 16; ++i) if (red_k[i] < m) m = red_k[i];
      best_s = m;
    }
    __syncthreads();
    chosen[r] = best_s;
  }

  int c0 = (int)(chosen[0] & 0xFFFFFFFFull);
  int c1 = (int)(chosen[1] & 0xFFFFFFFFull);
  int c2 = (int)(chosen[2] & 0xFFFFFFFFull);
  int c3 = (int)(chosen[3] & 0xFFFFFFFFull);

  #pragma unroll
  for (int i = 0; i < 4; ++i) {
    int n0 = i * 4096 + tid * 4;
    float4 v;
    v.x = (n0 + 0 == c0 || n0 + 0 == c1 || n0 + 0 == c2 || n0 + 0 == c3) ? 1.0f : 0.0f;
    v.y = (n0 + 1 == c0 || n0 + 1 == c1 || n0 + 1 == c2 || n0 + 1 == c3) ? 1.0f : 0.0f;
    v.z = (n0 + 2 == c0 || n0 + 2 == c1 || n0 + 2 == c2 || n0 + 2 == c3) ? 1.0f : 0.0f;
    v.w = (n0 + 3 == c0 || n0 + 3 == c1 || n0 + 3 == c2 || n0 + 3 == c3) ? 1.0f : 0.0f;
    *(float4*)(wlu_out + n0) = v;
  }
}

extern "C" void kernel_launch(void* const* d_in, const int* in_sizes, int n_in,
                              void* d_out, int out_size, void* d_ws, size_t ws_size,
                              hipStream_t stream) {
  const float* emb    = (const float*)d_in[0];  // (B, C)
  const float* w_prev = (const float*)d_in[1];  // (B, 3, N)
  const float* memory = (const float*)d_in[2];  // (B, N, M)
  const float* W      = (const float*)d_in[3];  // (M+2, C)
  const float* bias   = (const float*)d_in[4];  // (M+2,)
  // d_in[5] = n (always 4; hard-coded in k3_finish)

  float* out = (float*)d_out;
  float* w_out   = out;                            // B*3*N
  float* new_mem = out + (size_t)Bn * 3 * Nn;      // B*N*M

  float* ws       = (float*)d_ws;
  float* ws_k     = ws;                            // B*M
  float* ws_beta  = ws_k + (size_t)Bn * Mn;        // B
  float* ws_g     = ws_beta + Bn;                  // B
  float* ws_normk = ws_g + Bn;                     // B
  float* ws_denom = ws_normk + Bn;                 // B
  float* ws_p     = ws_denom + Bn;                 // B*N (unnormalized softmax numerators)

  k1_proj<<<Bn, 128, 0, stream>>>(emb, W, bias, ws_k, ws_beta, ws_g, ws_normk, ws_denom);
  k2_main<<<Bn * (Nn / 16), 256, 0, stream>>>(memory, w_prev, ws_k, ws_g, ws_normk,
                                              ws_beta, ws_p, new_mem, ws_denom);
  k3_finish<<<Bn, 1024, 0, stream>>>(w_prev, ws_p, ws_g, ws_denom, w_out);
}

// Round 2
// 475.868 us; speedup vs baseline: 5.1457x; 5.1457x over previous
//
#include <hip/hip_runtime.h>
#include <math.h>

#define Bn 64
#define Nn 16384
#define Mn 64
#define Cn 256
#define MP2 66
#define GAMMA 0.95f
#define EPSF 1e-16f

// ---------------- Kernel 1: projection o = emb @ W^T + b -> k, beta, g, ||k|| ----------------
__global__ __launch_bounds__(128) void k1_proj(
    const float* __restrict__ emb, const float* __restrict__ W,
    const float* __restrict__ bias,
    float* __restrict__ ws_k, float* __restrict__ ws_beta,
    float* __restrict__ ws_g, float* __restrict__ ws_normk) {
  int b = blockIdx.x;
  int tid = threadIdx.x;
  __shared__ float emb_s[Cn];
  __shared__ float k_s[Mn];
  for (int c = tid; c < Cn; c += blockDim.x) emb_s[c] = emb[(size_t)b * Cn + c];
  __syncthreads();
  if (tid < MP2) {
    float sum = bias[tid];
    const float* wrow = W + (size_t)tid * Cn;
    #pragma unroll 4
    for (int c = 0; c < Cn; ++c) sum += emb_s[c] * wrow[c];
    if (tid < Mn) {
      ws_k[(size_t)b * Mn + tid] = sum;
      k_s[tid] = sum;
    } else if (tid == Mn) {
      // stable softplus: max(x,0) + log1p(exp(-|x|))
      ws_beta[b] = fmaxf(sum, 0.0f) + log1pf(expf(-fabsf(sum)));
    } else {
      ws_g[b] = 1.0f / (1.0f + expf(-sum));
    }
  }
  __syncthreads();
  if (tid < 64) {
    float v = k_s[tid] * k_s[tid];
    #pragma unroll
    for (int o = 32; o > 0; o >>= 1) v += __shfl_xor(v, o, 64);
    if (tid == 0) ws_normk[b] = sqrtf(v);
  }
}

// ---------------- Kernel 2: fused cosine-sim + exp + memory update (pure streaming) ----------------
// One 16-lane group per memory row (M=64 floats = 16 x float4). 4 rows per wave,
// 16 rows per 256-thread block. Reads memory once; writes new_memory + unnormalized p.
// Softmax shift uses the constant bound beta (sim <= 1): p = exp(beta*(sim-1)).
// NO atomics (round-1 lesson: 262k same-line atomicAdds serialized -> 2.2 ms).
// Denominator is summed by k3, which reads p anyway.
__global__ __launch_bounds__(256) void k2_main(
    const float* __restrict__ memory, const float* __restrict__ w_prev,
    const float* __restrict__ ws_k, const float* __restrict__ ws_g,
    const float* __restrict__ ws_normk, const float* __restrict__ ws_beta,
    float* __restrict__ p_out, float* __restrict__ new_mem) {
  const int ROWS_PER_BLOCK = 16;
  const int blocks_per_b = Nn / ROWS_PER_BLOCK;  // 1024
  int b = blockIdx.x / blocks_per_b;
  int n_base = (blockIdx.x % blocks_per_b) * ROWS_PER_BLOCK;
  int tid = threadIdx.x;
  int wave = tid >> 6;
  int lane = tid & 63;
  int row_in_wave = lane >> 4;   // 0..3
  int col4 = lane & 15;          // which float4 of the row
  int n = n_base + wave * 4 + row_in_wave;

  size_t off = ((size_t)b * Nn + n) * Mn + (size_t)col4 * 4;
  const float4 m4 = *(const float4*)(memory + off);
  const float4 k4 = *(const float4*)(ws_k + (size_t)b * Mn + (size_t)col4 * 4);

  float g = ws_g[b];
  float wr_p  = w_prev[((size_t)b * 3 + 1) * Nn + n];
  float wlu_p = w_prev[((size_t)b * 3 + 2) * Nn + n];
  float ww = g * wr_p + (1.0f - g) * wlu_p;

  float dkm = m4.x * k4.x + m4.y * k4.y + m4.z * k4.z + m4.w * k4.w;
  float dmm = m4.x * m4.x + m4.y * m4.y + m4.z * m4.z + m4.w * m4.w;
  #pragma unroll
  for (int o = 8; o >= 1; o >>= 1) {   // reduce within 16-lane groups
    dkm += __shfl_xor(dkm, o, 64);
    dmm += __shfl_xor(dmm, o, 64);
  }

  float4 o4;
  o4.x = m4.x + ww * k4.x;
  o4.y = m4.y + ww * k4.y;
  o4.z = m4.z + ww * k4.z;
  o4.w = m4.w + ww * k4.w;
  *(float4*)(new_mem + off) = o4;

  if (col4 == 0) {
    float sim = dkm / (ws_normk[b] * sqrtf(dmm) + EPSF);
    float beta = ws_beta[b];
    p_out[(size_t)b * Nn + n] = expf(beta * (sim - 1.0f));
  }
}

// ---------------- Kernel 3: denom-sum, normalize, w_u, top-4 min -> w planes ----------------
// Single reduction phase (sum of p); max pass eliminated by the constant softmax shift.
// Vectorized float4 I/O throughout.
__global__ __launch_bounds__(1024) void k3_finish(
    const float* __restrict__ w_prev, const float* __restrict__ p_in,
    const float* __restrict__ ws_g, float* __restrict__ w_out) {
  int b = blockIdx.x;
  int tid = threadIdx.x;
  int lane = tid & 63, wid = tid >> 6;  // 16 waves
  float g = ws_g[b];

  const float* pb     = p_in   + (size_t)b * Nn;
  const float* wup_p  = w_prev + ((size_t)b * 3 + 0) * Nn;
  const float* wrp_p  = w_prev + ((size_t)b * 3 + 1) * Nn;
  const float* wlup_p = w_prev + ((size_t)b * 3 + 2) * Nn;
  float* wu_out  = w_out + ((size_t)b * 3 + 0) * Nn;
  float* wr_out  = w_out + ((size_t)b * 3 + 1) * Nn;
  float* wlu_out = w_out + ((size_t)b * 3 + 2) * Nn;

  // Phase A: load p (16 elems/thread as 4 x float4), sum-reduce for the denominator.
  float p_loc[16];
  float lsum = 0.0f;
  #pragma unroll
  for (int i = 0; i < 4; ++i) {
    int n0 = i * 4096 + tid * 4;
    float4 p4 = *(const float4*)(pb + n0);
    p_loc[i * 4 + 0] = p4.x;
    p_loc[i * 4 + 1] = p4.y;
    p_loc[i * 4 + 2] = p4.z;
    p_loc[i * 4 + 3] = p4.w;
    lsum += p4.x + p4.y + p4.z + p4.w;
  }
  #pragma unroll
  for (int o = 32; o > 0; o >>= 1) lsum += __shfl_xor(lsum, o, 64);

  __shared__ float red_f[16];
  __shared__ float bcast_f;
  if (lane == 0) red_f[wid] = lsum;
  __syncthreads();
  if (tid == 0) {
    float s = 0.0f;
    for (int i = 0; i < 16; ++i) s += red_f[i];
    bcast_f = s;
  }
  __syncthreads();
  float inv = 1.0f / bcast_f;

  // Phase B: normalize, compute w_w / w_u, write wu & wr planes; build top-k keys.
  unsigned long long key_loc[16];
  #pragma unroll
  for (int i = 0; i < 4; ++i) {
    int n0 = i * 4096 + tid * 4;
    float4 u4 = *(const float4*)(wup_p + n0);
    float4 r4 = *(const float4*)(wrp_p + n0);
    float4 l4 = *(const float4*)(wlup_p + n0);
    float4 wr4, wu4;
    wr4.x = p_loc[i * 4 + 0] * inv;
    wr4.y = p_loc[i * 4 + 1] * inv;
    wr4.z = p_loc[i * 4 + 2] * inv;
    wr4.w = p_loc[i * 4 + 3] * inv;
    wu4.x = GAMMA * u4.x + wr4.x + (g * r4.x + (1.0f - g) * l4.x);
    wu4.y = GAMMA * u4.y + wr4.y + (g * r4.y + (1.0f - g) * l4.y);
    wu4.z = GAMMA * u4.z + wr4.z + (g * r4.z + (1.0f - g) * l4.z);
    wu4.w = GAMMA * u4.w + wr4.w + (g * r4.w + (1.0f - g) * l4.w);
    *(float4*)(wu_out + n0) = wu4;
    *(float4*)(wr_out + n0) = wr4;
    // unique orderable key = (flipped_float_bits << 32) | index
    #pragma unroll
    for (int j = 0; j < 4; ++j) {
      float v = (j == 0) ? wu4.x : (j == 1) ? wu4.y : (j == 2) ? wu4.z : wu4.w;
      unsigned int bits = __float_as_uint(v);
      bits ^= (bits >> 31) ? 0xFFFFFFFFu : 0x80000000u;  // total order incl. negatives
      key_loc[i * 4 + j] =
          ((unsigned long long)bits << 32) | (unsigned int)(n0 + j);
    }
  }

  // top-4 smallest w_u, ties -> lower index (matches jax.lax.top_k on -w_u).
  __shared__ unsigned long long red_k[16];
  __shared__ unsigned long long best_s;
  unsigned long long chosen[4] = {~0ull, ~0ull, ~0ull, ~0ull};

  for (int r = 0; r < 4; ++r) {
    unsigned long long bk = ~0ull;
    #pragma unroll
    for (int i = 0; i < 16; ++i) {
      unsigned long long k = key_loc[i];
      bool excl = (k == chosen[0]) | (k == chosen[1]) | (k == chosen[2]) | (k == chosen[3]);
      if (!excl && k < bk) bk = k;
    }
    #pragma unroll
    for (int o = 32; o > 0; o >>= 1) {
      unsigned long long ok = __shfl_xor(bk, o, 64);
      if (ok < bk) bk = ok;
    }
    if (lane == 0) red_k[wid] = bk;
    __syncthreads();
    if (tid == 0) {
      unsigned long long m = red_k[0];
      for (int i = 1; i < 16; ++i) if (red_k[i] < m) m = red_k[i];
      best_s = m;
    }
    __syncthreads();
    chosen[r] = best_s;
  }

  int c0 = (int)(chosen[0] & 0xFFFFFFFFull);
  int c1 = (int)(chosen[1] & 0xFFFFFFFFull);
  int c2 = (int)(chosen[2] & 0xFFFFFFFFull);
  int c3 = (int)(chosen[3] & 0xFFFFFFFFull);

  #pragma unroll
  for (int i = 0; i < 4; ++i) {
    int n0 = i * 4096 + tid * 4;
    float4 v;
    v.x = (n0 + 0 == c0 || n0 + 0 == c1 || n0 + 0 == c2 || n0 + 0 == c3) ? 1.0f : 0.0f;
    v.y = (n0 + 1 == c0 || n0 + 1 == c1 || n0 + 1 == c2 || n0 + 1 == c3) ? 1.0f : 0.0f;
    v.z = (n0 + 2 == c0 || n0 + 2 == c1 || n0 + 2 == c2 || n0 + 2 == c3) ? 1.0f : 0.0f;
    v.w = (n0 + 3 == c0 || n0 + 3 == c1 || n0 + 3 == c2 || n0 + 3 == c3) ? 1.0f : 0.0f;
    *(float4*)(wlu_out + n0) = v;
  }
}

extern "C" void kernel_launch(void* const* d_in, const int* in_sizes, int n_in,
                              void* d_out, int out_size, void* d_ws, size_t ws_size,
                              hipStream_t stream) {
  const float* emb    = (const float*)d_in[0];  // (B, C)
  const float* w_prev = (const float*)d_in[1];  // (B, 3, N)
  const float* memory = (const float*)d_in[2];  // (B, N, M)
  const float* W      = (const float*)d_in[3];  // (M+2, C)
  const float* bias   = (const float*)d_in[4];  // (M+2,)
  // d_in[5] = n (always 4; hard-coded in k3_finish)

  float* out = (float*)d_out;
  float* w_out   = out;                            // B*3*N
  float* new_mem = out + (size_t)Bn * 3 * Nn;      // B*N*M

  float* ws       = (float*)d_ws;
  float* ws_k     = ws;                            // B*M
  float* ws_beta  = ws_k + (size_t)Bn * Mn;        // B
  float* ws_g     = ws_beta + Bn;                  // B
  float* ws_normk = ws_g + Bn;                     // B
  float* ws_p     = ws_normk + Bn;                 // B*N (unnormalized softmax numerators)

  k1_proj<<<Bn, 128, 0, stream>>>(emb, W, bias, ws_k, ws_beta, ws_g, ws_normk);
  k2_main<<<Bn * (Nn / 16), 256, 0, stream>>>(memory, w_prev, ws_k, ws_g, ws_normk,
                                              ws_beta, ws_p, new_mem);
  k3_finish<<<Bn, 1024, 0, stream>>>(w_prev, ws_p, ws_g, w_out);
}

// Round 3
// 474.179 us; speedup vs baseline: 5.1640x; 1.0036x over previous
//
#include <hip/hip_runtime.h>
#include <math.h>

#define Bn 64
#define Nn 16384
#define Mn 64
#define Cn 256
#define MP2 66
#define GAMMA 0.95f
#define EPSF 1e-16f

#define K3A_BLKS_PER_B 16                 // 1024 blocks total, 256 thr each
#define K2_BLKS_PER_B (Nn / 16)           // 1024

// ---------------- Kernel 1: projection o = emb @ W^T + b -> k, beta, g, ||k|| ----------------
__global__ __launch_bounds__(128) void k1_proj(
    const float* __restrict__ emb, const float* __restrict__ W,
    const float* __restrict__ bias,
    float* __restrict__ ws_k, float* __restrict__ ws_beta,
    float* __restrict__ ws_g, float* __restrict__ ws_normk) {
  int b = blockIdx.x;
  int tid = threadIdx.x;
  __shared__ float emb_s[Cn];
  __shared__ float k_s[Mn];
  for (int c = tid; c < Cn; c += blockDim.x) emb_s[c] = emb[(size_t)b * Cn + c];
  __syncthreads();
  if (tid < MP2) {
    float sum = bias[tid];
    const float* wrow = W + (size_t)tid * Cn;
    #pragma unroll 4
    for (int c = 0; c < Cn; ++c) sum += emb_s[c] * wrow[c];
    if (tid < Mn) {
      ws_k[(size_t)b * Mn + tid] = sum;
      k_s[tid] = sum;
    } else if (tid == Mn) {
      // stable softplus: max(x,0) + log1p(exp(-|x|))
      ws_beta[b] = fmaxf(sum, 0.0f) + log1pf(expf(-fabsf(sum)));
    } else {
      ws_g[b] = 1.0f / (1.0f + expf(-sum));
    }
  }
  __syncthreads();
  if (tid < 64) {
    float v = k_s[tid] * k_s[tid];
    #pragma unroll
    for (int o = 32; o > 0; o >>= 1) v += __shfl_xor(v, o, 64);
    if (tid == 0) ws_normk[b] = sqrtf(v);
  }
}

// ---------------- Kernel 2: fused cosine-sim + exp + memory update (pure streaming) ----------------
// One 16-lane group per memory row (M=64 floats = 16 x float4). 4 rows per wave,
// 16 rows per 256-thread block. Reads memory once; writes new_memory + unnormalized p
// + one per-block partial sum of p (no atomics — round-1 lesson: same-line atomicAdd
// serialized the whole grid to 2.2 ms).
// Softmax shift uses the constant bound beta (sim <= 1): p = exp(beta*(sim-1)).
__global__ __launch_bounds__(256) void k2_main(
    const float* __restrict__ memory, const float* __restrict__ w_prev,
    const float* __restrict__ ws_k, const float* __restrict__ ws_g,
    const float* __restrict__ ws_normk, const float* __restrict__ ws_beta,
    float* __restrict__ p_out, float* __restrict__ new_mem,
    float* __restrict__ ws_psum) {
  const int ROWS_PER_BLOCK = 16;
  int b = blockIdx.x / K2_BLKS_PER_B;
  int n_base = (blockIdx.x % K2_BLKS_PER_B) * ROWS_PER_BLOCK;
  int tid = threadIdx.x;
  int wave = tid >> 6;
  int lane = tid & 63;
  int row_in_wave = lane >> 4;   // 0..3
  int col4 = lane & 15;          // which float4 of the row
  int n = n_base + wave * 4 + row_in_wave;

  size_t off = ((size_t)b * Nn + n) * Mn + (size_t)col4 * 4;
  const float4 m4 = *(const float4*)(memory + off);
  const float4 k4 = *(const float4*)(ws_k + (size_t)b * Mn + (size_t)col4 * 4);

  float g = ws_g[b];
  float wr_p  = w_prev[((size_t)b * 3 + 1) * Nn + n];
  float wlu_p = w_prev[((size_t)b * 3 + 2) * Nn + n];
  float ww = g * wr_p + (1.0f - g) * wlu_p;

  float dkm = m4.x * k4.x + m4.y * k4.y + m4.z * k4.z + m4.w * k4.w;
  float dmm = m4.x * m4.x + m4.y * m4.y + m4.z * m4.z + m4.w * m4.w;
  #pragma unroll
  for (int o = 8; o >= 1; o >>= 1) {   // reduce within 16-lane groups
    dkm += __shfl_xor(dkm, o, 64);
    dmm += __shfl_xor(dmm, o, 64);
  }

  float4 o4;
  o4.x = m4.x + ww * k4.x;
  o4.y = m4.y + ww * k4.y;
  o4.z = m4.z + ww * k4.z;
  o4.w = m4.w + ww * k4.w;
  *(float4*)(new_mem + off) = o4;

  float sim = dkm / (ws_normk[b] * sqrtf(dmm) + EPSF);
  float e = expf(ws_beta[b] * (sim - 1.0f));   // unnormalized prob, const shift
  if (col4 == 0) p_out[(size_t)b * Nn + n] = e;

  // per-block partial denom: lanes 0,16,32,48 hold the 4 distinct row values
  __shared__ float esum_s[4];
  float ec = (col4 == 0) ? e : 0.0f;
  ec += __shfl_xor(ec, 16, 64);
  ec += __shfl_xor(ec, 32, 64);
  if (lane == 0) esum_s[wave] = ec;
  __syncthreads();
  if (tid == 0)
    ws_psum[blockIdx.x] = esum_s[0] + esum_s[1] + esum_s[2] + esum_s[3];
}

// ---------------- Kernel 3a: denom from partials, normalize, w_u, per-block top-4 ----------------
// 16 blocks per batch (1024 blocks total) -> full-chip bandwidth for the 29 MB pass.
// Writes wu/wr planes, zeros the wlu plane, emits 4 top-candidate keys per block.
__global__ __launch_bounds__(256) void k3a_norm(
    const float* __restrict__ w_prev, const float* __restrict__ p_in,
    const float* __restrict__ ws_g, const float* __restrict__ ws_psum,
    float* __restrict__ w_out, unsigned long long* __restrict__ ws_top) {
  int b = blockIdx.x / K3A_BLKS_PER_B;
  int blk = blockIdx.x % K3A_BLKS_PER_B;
  int tid = threadIdx.x;
  int lane = tid & 63, wid = tid >> 6;  // 4 waves
  float g = ws_g[b];

  __shared__ float red_f[4];
  __shared__ float bcast_f;

  // denominator: sum this batch's 1024 per-k2-block partials (4 KB, L2-hit)
  {
    float4 s4 = *(const float4*)(ws_psum + (size_t)b * K2_BLKS_PER_B + tid * 4);
    float s = s4.x + s4.y + s4.z + s4.w;
    #pragma unroll
    for (int o = 32; o > 0; o >>= 1) s += __shfl_xor(s, o, 64);
    if (lane == 0) red_f[wid] = s;
    __syncthreads();
    if (tid == 0) bcast_f = red_f[0] + red_f[1] + red_f[2] + red_f[3];
    __syncthreads();
  }
  float inv = 1.0f / bcast_f;

  const float* pb     = p_in   + (size_t)b * Nn;
  const float* wup_p  = w_prev + ((size_t)b * 3 + 0) * Nn;
  const float* wrp_p  = w_prev + ((size_t)b * 3 + 1) * Nn;
  const float* wlup_p = w_prev + ((size_t)b * 3 + 2) * Nn;
  float* wu_out  = w_out + ((size_t)b * 3 + 0) * Nn;
  float* wr_out  = w_out + ((size_t)b * 3 + 1) * Nn;
  float* wlu_out = w_out + ((size_t)b * 3 + 2) * Nn;

  // this block's 1024-element slice: one float4 per thread
  int n0 = blk * (Nn / K3A_BLKS_PER_B) + tid * 4;
  float4 p4 = *(const float4*)(pb + n0);
  float4 u4 = *(const float4*)(wup_p + n0);
  float4 r4 = *(const float4*)(wrp_p + n0);
  float4 l4 = *(const float4*)(wlup_p + n0);
  float4 wr4, wu4;
  wr4.x = p4.x * inv; wr4.y = p4.y * inv; wr4.z = p4.z * inv; wr4.w = p4.w * inv;
  wu4.x = GAMMA * u4.x + wr4.x + (g * r4.x + (1.0f - g) * l4.x);
  wu4.y = GAMMA * u4.y + wr4.y + (g * r4.y + (1.0f - g) * l4.y);
  wu4.z = GAMMA * u4.z + wr4.z + (g * r4.z + (1.0f - g) * l4.z);
  wu4.w = GAMMA * u4.w + wr4.w + (g * r4.w + (1.0f - g) * l4.w);
  *(float4*)(wu_out + n0) = wu4;
  *(float4*)(wr_out + n0) = wr4;
  float4 z4 = make_float4(0.0f, 0.0f, 0.0f, 0.0f);
  *(float4*)(wlu_out + n0) = z4;   // k3b overwrites the 4 chosen entries

  // unique orderable keys: (flipped_float_bits << 32) | index
  unsigned long long key[4];
  {
    float v[4] = {wu4.x, wu4.y, wu4.z, wu4.w};
    #pragma unroll
    for (int j = 0; j < 4; ++j) {
      unsigned int bits = __float_as_uint(v[j]);
      bits ^= (bits >> 31) ? 0xFFFFFFFFu : 0x80000000u;  // total order incl. negatives
      key[j] = ((unsigned long long)bits << 32) | (unsigned int)(n0 + j);
    }
  }

  // block-local top-4 smallest (ties -> lower index via key uniqueness)
  __shared__ unsigned long long red_k[4];
  __shared__ unsigned long long chosen_s[4];
  unsigned long long chosen[4] = {~0ull, ~0ull, ~0ull, ~0ull};
  for (int r = 0; r < 4; ++r) {
    unsigned long long bk = ~0ull;
    #pragma unroll
    for (int j = 0; j < 4; ++j) {
      unsigned long long k = key[j];
      bool excl = (k == chosen[0]) | (k == chosen[1]) | (k == chosen[2]) | (k == chosen[3]);
      if (!excl && k < bk) bk = k;
    }
    #pragma unroll
    for (int o = 32; o > 0; o >>= 1) {
      unsigned long long ok = __shfl_xor(bk, o, 64);
      if (ok < bk) bk = ok;
    }
    if (lane == 0) red_k[wid] = bk;
    __syncthreads();
    if (tid == 0) {
      unsigned long long m = red_k[0];
      for (int i = 1; i < 4; ++i) if (red_k[i] < m) m = red_k[i];
      chosen_s[r] = m;
    }
    __syncthreads();
    chosen[r] = chosen_s[r];
  }
  if (tid < 4) ws_top[(size_t)blockIdx.x * 4 + tid] = chosen_s[tid];
}

// ---------------- Kernel 3b: final top-4 per batch from 64 candidates, scatter ones ----------------
__global__ __launch_bounds__(64) void k3b_scatter(
    const unsigned long long* __restrict__ ws_top, float* __restrict__ w_out) {
  int b = blockIdx.x;
  int lane = threadIdx.x;
  unsigned long long k = ws_top[(size_t)b * (K3A_BLKS_PER_B * 4) + lane];
  float* wlu_out = w_out + ((size_t)b * 3 + 2) * Nn;
  #pragma unroll
  for (int r = 0; r < 4; ++r) {
    unsigned long long m = k;
    #pragma unroll
    for (int o = 32; o > 0; o >>= 1) {
      unsigned long long om = __shfl_xor(m, o, 64);
      if (om < m) m = om;
    }
    if (k == m) k = ~0ull;             // keys unique -> exactly one lane invalidates
    if (lane == r) wlu_out[(unsigned int)(m & 0xFFFFFFFFull)] = 1.0f;
  }
}

extern "C" void kernel_launch(void* const* d_in, const int* in_sizes, int n_in,
                              void* d_out, int out_size, void* d_ws, size_t ws_size,
                              hipStream_t stream) {
  const float* emb    = (const float*)d_in[0];  // (B, C)
  const float* w_prev = (const float*)d_in[1];  // (B, 3, N)
  const float* memory = (const float*)d_in[2];  // (B, N, M)
  const float* W      = (const float*)d_in[3];  // (M+2, C)
  const float* bias   = (const float*)d_in[4];  // (M+2,)
  // d_in[5] = n (always 4; hard-coded top-4)

  float* out = (float*)d_out;
  float* w_out   = out;                            // B*3*N
  float* new_mem = out + (size_t)Bn * 3 * Nn;      // B*N*M

  float* ws       = (float*)d_ws;
  float* ws_k     = ws;                            // B*M
  float* ws_beta  = ws_k + (size_t)Bn * Mn;        // B
  float* ws_g     = ws_beta + Bn;                  // B
  float* ws_normk = ws_g + Bn;                     // B
  float* ws_p     = ws_normk + Bn;                 // B*N
  float* ws_psum  = ws_p + (size_t)Bn * Nn;        // B*1024 per-k2-block partials
  unsigned long long* ws_top =
      (unsigned long long*)(ws_psum + (size_t)Bn * K2_BLKS_PER_B);  // B*64 keys (8B-aligned)

  k1_proj<<<Bn, 128, 0, stream>>>(emb, W, bias, ws_k, ws_beta, ws_g, ws_normk);
  k2_main<<<Bn * K2_BLKS_PER_B, 256, 0, stream>>>(memory, w_prev, ws_k, ws_g, ws_normk,
                                                  ws_beta, ws_p, new_mem, ws_psum);
  k3a_norm<<<Bn * K3A_BLKS_PER_B, 256, 0, stream>>>(w_prev, ws_p, ws_g, ws_psum,
                                                    w_out, ws_top);
  k3b_scatter<<<Bn, 64, 0, stream>>>(ws_top, w_out);
}